// Round 14
// baseline (278.993 us; speedup 1.0000x reference)
//
#include <hip/hip_runtime.h>
#include <math.h>

#define B_DIM 128
#define N_DIM 512
#define D_DIM 512
#define H_DIM 256
#define K_SEL 8

typedef _Float16 half8 __attribute__((ext_vector_type(8)));
typedef float    f32x4 __attribute__((ext_vector_type(4)));

// ---------------- Kernel 0: prep W1 -> transposed fp16 2-way split (l scaled by 2048) ----
// x = h + l'/2048 + eps, |eps| <= 2^-22|x|. Scaling keeps l' in fp16 normal range.
__global__ __launch_bounds__(256) void prep_w1_kernel(
    const float* __restrict__ W1,
    _Float16* __restrict__ w1t_h,
    _Float16* __restrict__ w1t_l)
{
    const int c = blockIdx.x;      // 256 cols
    const int t = threadIdx.x;     // 256 threads over k
    #pragma unroll
    for (int kk = 0; kk < D_DIM; kk += 256) {
        int k = kk + t;
        float x = W1[(size_t)k * H_DIM + c];
        _Float16 h = (_Float16)x;
        float r = x - (float)h;
        w1t_h[(size_t)c * D_DIM + k] = h;
        w1t_l[(size_t)c * D_DIM + k] = (_Float16)(r * 2048.0f);
    }
}

// ---------------- Kernel 1: LDS-free, barrier-free swapped-operand MFMA scorer --------
// Compute h^T = W1^T (A operand) x X^T (B operand) with mfma_f32_16x16x32_f16.
//  - A-frag: lane reads w1t[hidden=m*16+l15][k=ks*32+lg*8 ..+7] — 16 B contiguous,
//    identical across waves (L1-broadcast), layout == prep output.
//  - B-frag: lane reads X[token=tok0+l15][same k] from GLOBAL, f32 -> fp16 h/l'
//    split IN-REGISTER. MFMA B-layout == X row-major => no LDS, no transpose,
//    no __syncthreads anywhere (r4-r13's ~7 us/k-step barrier+staging structure
//    was the invariant bottleneck).
// Per wave: 16 tokens x 256 hidden; acc = 16 m-tiles x f32x4 = 64 VGPR.
// D-layout: token = lane&15, hidden = m*16 + (lane>>4)*4 + r.
// Grid: 512 WGs x 512 thr (4096 waves x 16 tokens = 65536 rows), no LDS ->
// 2 WGs/CU resident; (512,2) => measured 128-VGPR cap (r7/r12), live ~105.
__global__ __launch_bounds__(512, 2) void fused_scorer_mfma(
    const float* __restrict__ X,           // (65536, 512)
    const _Float16* __restrict__ w1t_h,    // (256, 512) [col][k]
    const _Float16* __restrict__ w1t_l,
    const float* __restrict__ b1,          // (256)
    const float* __restrict__ W2,          // (256)
    const float* __restrict__ b2p,         // scalar
    const float* __restrict__ base_logits, // (512)
    float* __restrict__ logits)            // (65536)
{
    const int tid  = threadIdx.x;
    const int lane = tid & 63;
    const int l15  = lane & 15;
    const int lg   = lane >> 4;           // 0..3 (k-group)
    const int tok0 = (blockIdx.x * 8 + (tid >> 6)) * 16;

    const float*    xp = X     + (size_t)(tok0 + l15) * D_DIM + lg * 8;
    const _Float16* wh = w1t_h + (size_t)l15 * D_DIM + lg * 8;   // + m*16*D + ks*32
    const _Float16* wl = w1t_l + (size_t)l15 * D_DIM + lg * 8;

    f32x4 acc[16];
    #pragma unroll
    for (int m = 0; m < 16; ++m) acc[m] = (f32x4){0.f, 0.f, 0.f, 0.f};

    // prefetch X(ks=0)
    float4 xa = *reinterpret_cast<const float4*>(xp);
    float4 xb = *reinterpret_cast<const float4*>(xp + 4);

    for (int ks = 0; ks < 16; ++ks) {
        // in-register split of this k-step's 8 X values -> B-frags
        float e[8] = {xa.x, xa.y, xa.z, xa.w, xb.x, xb.y, xb.z, xb.w};
        half8 bh, bl;
        #pragma unroll
        for (int j = 0; j < 8; ++j) {
            _Float16 h = (_Float16)e[j];
            float r = e[j] - (float)h;
            bh[j] = h;
            bl[j] = (_Float16)(r * 2048.0f);
        }
        // prefetch next X under this step's MFMAs
        if (ks < 15) {
            xa = *reinterpret_cast<const float4*>(xp + (ks + 1) * 32);
            xb = *reinterpret_cast<const float4*>(xp + (ks + 1) * 32 + 4);
        }
        const int ko = ks * 32;
        #pragma unroll
        for (int m = 0; m < 16; ++m) {
            size_t wo = (size_t)m * 16 * D_DIM + ko;
            half8 ah = *reinterpret_cast<const half8*>(wh + wo);
            half8 al = *reinterpret_cast<const half8*>(wl + wo);
            acc[m] = __builtin_amdgcn_mfma_f32_16x16x32_f16(ah, bh, acc[m], 0, 0, 0);
            f32x4 t = __builtin_amdgcn_mfma_f32_16x16x32_f16(ah, bl, (f32x4){0.f,0.f,0.f,0.f}, 0, 0, 0);
            t = __builtin_amdgcn_mfma_f32_16x16x32_f16(al, bh, t, 0, 0, 0);
            acc[m] += t * (1.0f / 2048.0f);
        }
    }

    // ---- epilogue: z = acc + b1 ; exact GELU ; dot W2 ; reduce over lg ; write ----
    float part = 0.f;
    #pragma unroll
    for (int m = 0; m < 16; ++m) {
        float4 b1v = *reinterpret_cast<const float4*>(b1 + m * 16 + lg * 4);
        float4 w2v = *reinterpret_cast<const float4*>(W2 + m * 16 + lg * 4);
        float bb[4] = {b1v.x, b1v.y, b1v.z, b1v.w};
        float ww[4] = {w2v.x, w2v.y, w2v.z, w2v.w};
        #pragma unroll
        for (int r = 0; r < 4; ++r) {
            float z = acc[m][r] + bb[r];
            float g = 0.5f * z * (1.0f + erff(z * 0.70710678118654752440f));
            part = fmaf(g, ww[r], part);
        }
    }
    part += __shfl_xor(part, 16, 64);
    part += __shfl_xor(part, 32, 64);
    if (lane < 16) {
        int row = tok0 + lane;
        logits[row] = part + b2p[0] + base_logits[row & (N_DIM - 1)];
    }
}

// ---------------- Kernel 2: softmax + top-8 + mask/importance/indices ----------------
__global__ __launch_bounds__(256) void softmax_topk_kernel(
    const float* __restrict__ logits,
    float* __restrict__ out_mask,
    float* __restrict__ out_importance,
    float* __restrict__ out_indices)
{
    const int b = blockIdx.x;
    const int tid = threadIdx.x;
    __shared__ float probs[N_DIM];
    __shared__ float redf[4];
    __shared__ int   redi[4];
    __shared__ int   sel_idx[K_SEL];

    float l0 = logits[b * N_DIM + tid];
    float l1 = logits[b * N_DIM + tid + 256];

    float m = fmaxf(l0, l1);
    #pragma unroll
    for (int s = 32; s >= 1; s >>= 1) m = fmaxf(m, __shfl_xor(m, s, 64));
    if ((tid & 63) == 0) redf[tid >> 6] = m;
    __syncthreads();
    float gm = fmaxf(fmaxf(redf[0], redf[1]), fmaxf(redf[2], redf[3]));
    __syncthreads();

    float e0 = expf(l0 - gm), e1 = expf(l1 - gm);
    float ssum = e0 + e1;
    #pragma unroll
    for (int s = 32; s >= 1; s >>= 1) ssum += __shfl_xor(ssum, s, 64);
    if ((tid & 63) == 0) redf[tid >> 6] = ssum;
    __syncthreads();
    float denom = redf[0] + redf[1] + redf[2] + redf[3];
    float p0 = e0 / denom, p1 = e1 / denom;
    probs[tid] = p0;
    probs[tid + 256] = p1;
    out_importance[b * N_DIM + tid] = p0;
    out_importance[b * N_DIM + tid + 256] = p1;
    __syncthreads();

    for (int it = 0; it < K_SEL; ++it) {
        float v0 = probs[tid]; int i0 = tid;
        float v1 = probs[tid + 256];
        if (v1 > v0) { v0 = v1; i0 = tid + 256; }
        #pragma unroll
        for (int s = 32; s >= 1; s >>= 1) {
            float ov = __shfl_xor(v0, s, 64);
            int   oi = __shfl_xor(i0, s, 64);
            if (ov > v0 || (ov == v0 && oi < i0)) { v0 = ov; i0 = oi; }
        }
        if ((tid & 63) == 0) { redf[tid >> 6] = v0; redi[tid >> 6] = i0; }
        __syncthreads();
        if (tid == 0) {
            float bv = redf[0]; int bi = redi[0];
            for (int w = 1; w < 4; ++w)
                if (redf[w] > bv || (redf[w] == bv && redi[w] < bi)) { bv = redf[w]; bi = redi[w]; }
            sel_idx[it] = bi;
            probs[bi] = -1.0f;
        }
        __syncthreads();
    }

    float mk0 = 0.f, mk1 = 0.f;
    #pragma unroll
    for (int i = 0; i < K_SEL; ++i) {
        if (sel_idx[i] == tid)       mk0 = 1.f;
        if (sel_idx[i] == tid + 256) mk1 = 1.f;
    }
    out_mask[b * N_DIM + tid] = mk0;
    out_mask[b * N_DIM + tid + 256] = mk1;

    if (tid < K_SEL) out_indices[b * K_SEL + tid] = (float)sel_idx[tid];
}

// ---------------- Kernel 3: gather selected rows (overwrites scratch last) ----------
__global__ __launch_bounds__(256) void gather_kernel(
    const float* __restrict__ X,
    const float* __restrict__ out_indices,
    float* __restrict__ out_selected)
{
    const int b = blockIdx.x;
    const int tid = threadIdx.x;
    __shared__ int sel[K_SEL];
    if (tid < K_SEL) sel[tid] = (int)out_indices[b * K_SEL + tid];
    __syncthreads();
    #pragma unroll
    for (int i = 0; i < 4; ++i) {
        int f = tid + 256 * i;
        int ki = f >> 7;
        int c4 = f & 127;
        float4 v = reinterpret_cast<const float4*>(
            X + ((size_t)b * N_DIM + sel[ki]) * D_DIM)[c4];
        reinterpret_cast<float4*>(
            out_selected + ((size_t)b * K_SEL + ki) * D_DIM)[c4] = v;
    }
}

extern "C" void kernel_launch(void* const* d_in, const int* in_sizes, int n_in,
                              void* d_out, int out_size, void* d_ws, size_t ws_size,
                              hipStream_t stream) {
    const float* X           = (const float*)d_in[0];
    const float* W1          = (const float*)d_in[1];
    const float* b1          = (const float*)d_in[2];
    const float* W2          = (const float*)d_in[3];
    const float* b2          = (const float*)d_in[4];
    const float* base_logits = (const float*)d_in[5];

    float* out            = (float*)d_out;
    float* out_selected   = out;                                  // 128*8*512 = 524288
    float* out_mask       = out_selected + B_DIM * K_SEL * D_DIM; // 128*512
    float* out_importance = out_mask + B_DIM * N_DIM;             // 128*512
    float* out_indices    = out_importance + B_DIM * N_DIM;       // 128*8

    // Scratch inside out_selected's region (gather overwrites it last):
    float*    logits = out_selected;                         // [0, 65536) f32
    _Float16* w1t_h  = (_Float16*)(out_selected + 65536);    // 131072 halfs
    _Float16* w1t_l  = (_Float16*)(out_selected + 131072);   // 131072 halfs

    hipLaunchKernelGGL(prep_w1_kernel, dim3(H_DIM), dim3(256), 0, stream,
                       W1, w1t_h, w1t_l);
    hipLaunchKernelGGL(fused_scorer_mfma, dim3(512), dim3(512), 0, stream,
                       X, w1t_h, w1t_l, b1, W2, b2, base_logits, logits);
    hipLaunchKernelGGL(softmax_topk_kernel, dim3(B_DIM), dim3(256), 0, stream,
                       logits, out_mask, out_importance, out_indices);
    hipLaunchKernelGGL(gather_kernel, dim3(B_DIM), dim3(256), 0, stream,
                       X, out_indices, out_selected);
}

// Round 15
// 110.021 us; speedup vs baseline: 2.5358x; 2.5358x over previous
//
#include <hip/hip_runtime.h>
#include <math.h>

#define B_DIM 128
#define N_DIM 512
#define D_DIM 512
#define H_DIM 256
#define K_SEL 8

typedef _Float16 half8 __attribute__((ext_vector_type(8)));
typedef float    f32x4 __attribute__((ext_vector_type(4)));

// ---------------- Kernel 0: prep W1 -> MFMA-frag-ordered fp16 h/l' tables -------------
// Output layout: w1frag[(c4*16 + ks)*512 + lane*8 + j] holds the element MFMA lane
// `lane` needs at position j of its B-frag for hidden-col block c4, k-step ks:
//   col = c4*16 + (lane&15), k = ks*32 + (lane>>4)*8 + j.
// A wave's frag load is then base + lane*16B — one contiguous aligned 1 KB read.
// Split: x = h + l'/2048 + eps, |eps| <= 2^-22|x| (l' scaled into fp16 normal range).
__global__ __launch_bounds__(512) void prep_w1_kernel(
    const float* __restrict__ W1,          // (512, 256) [k][col]
    _Float16* __restrict__ w1frag_h,
    _Float16* __restrict__ w1frag_l)
{
    const int b    = blockIdx.x;           // 0..255 = c4*16 + ks
    const int c4   = b >> 4;
    const int ks   = b & 15;
    const int lane = threadIdx.x >> 3;     // 0..63
    const int j    = threadIdx.x & 7;
    const int col  = c4 * 16 + (lane & 15);
    const int k    = ks * 32 + (lane >> 4) * 8 + j;
    float x = W1[(size_t)k * H_DIM + col];
    _Float16 h = (_Float16)x;
    float r = x - (float)h;
    size_t o = (size_t)b * 512 + lane * 8 + j;
    w1frag_h[o] = h;
    w1frag_l[o] = (_Float16)(r * 2048.0f);
}

// ---------------- Kernel 1: fp16x2-split MFMA scorer, A-LDS only, 2 WGs/CU -----------
// Grid: 512 WGs = 256 row-tiles x 2 col-halves (pair shares an XCD -> L2 A-dedup),
// 512 threads, 8 waves 4Mx2N, per-wave 64x64 = 4x4 frags (acc 64 VGPR).
// A: f32 -> in-reg h/l' split -> chunk-major LDS dbuf (64 KB TOTAL -> two WGs/CU;
//    r12's 96 KB allowed only one -> barriers never overlapped, 22% occupancy).
// B: NO LDS — direct global reads of the frag-ordered table (1 KB/wave coalesced,
//    L2-resident). r14 proved scattered frag gathers are fatal; frag-ordering fixes it.
__global__ __launch_bounds__(512, 2) void fused_scorer_mfma(
    const float* __restrict__ X,           // (65536, 512)
    const _Float16* __restrict__ w1frag_h, // (131072) frag-ordered
    const _Float16* __restrict__ w1frag_l,
    const float* __restrict__ b1,          // (256)
    const float* __restrict__ W2,          // (256)
    float* __restrict__ lp)                // (2, 65536) partial logits
{
    // A chunk16 = half8; chunk index = kc*256 + row (kc 0..3, 8 k each)
    __shared__ half8 Ah[2][1024], Al[2][1024];   // 64 KB

    const int tid  = threadIdx.x;
    const int lane = tid & 63;
    const int wave = tid >> 6;            // 0..7
    const int wm   = (wave >> 1) << 6;    // 0,64,128,192
    const int wnx  = wave & 1;            // 0,1 -> cols wnx*64 within the half
    const int l15  = lane & 15;
    const int lg   = lane >> 4;           // 0..3
    const int rowtile = blockIdx.x & 255;
    const int colhalf = blockIdx.x >> 8;  // 0,1
    const int row0 = rowtile * 256;
    const int c4base = colhalf * 8 + wnx * 4;   // frag col-block base for this wave

    // A staging: thread t -> chunks t and t+512 (rc = t&255; kc = t>>8 and +2)
    const int rc  = tid & 255;
    const int kc1 = tid >> 8;
    const float* xp = X + (size_t)(row0 + rc) * D_DIM + kc1 * 8;

    // B frag base: + ((c4base+nj)*16 + ks)*512 halfs
    const _Float16* fbh_base = w1frag_h + (size_t)lane * 8;
    const _Float16* fbl_base = w1frag_l + (size_t)lane * 8;

    f32x4 acc[4][4];
    #pragma unroll
    for (int mi = 0; mi < 4; ++mi)
        #pragma unroll
        for (int nj = 0; nj < 4; ++nj)
            acc[mi][nj] = (f32x4){0.f, 0.f, 0.f, 0.f};

    float4 xv[4];
    auto load_a = [&](int k0) {
        xv[0] = *reinterpret_cast<const float4*>(xp + k0);
        xv[1] = *reinterpret_cast<const float4*>(xp + k0 + 4);
        xv[2] = *reinterpret_cast<const float4*>(xp + k0 + 16);   // chunk kc1+2
        xv[3] = *reinterpret_cast<const float4*>(xp + k0 + 20);
    };
    auto split_write = [&](int buf) {
        #pragma unroll
        for (int q = 0; q < 2; ++q) {
            float e[8] = {xv[2*q].x, xv[2*q].y, xv[2*q].z, xv[2*q].w,
                          xv[2*q+1].x, xv[2*q+1].y, xv[2*q+1].z, xv[2*q+1].w};
            half8 hh, ll;
            #pragma unroll
            for (int j = 0; j < 8; ++j) {
                _Float16 h = (_Float16)e[j];
                float r = e[j] - (float)h;
                hh[j] = h;
                ll[j] = (_Float16)(r * 2048.0f);
            }
            Ah[buf][tid + q * 512] = hh;
            Al[buf][tid + q * 512] = ll;
        }
    };

    // ---- prologue: stage A(0); prefetch A(1) ----
    load_a(0);
    split_write(0);
    load_a(32);
    __syncthreads();

    for (int ks = 0; ks < 16; ++ks) {
        const int buf = ks & 1, nbuf = buf ^ 1;
        if (ks < 15) {
            split_write(nbuf);                       // A(ks+1) regs -> LDS
            if (ks < 14) load_a((ks + 2) * 32);      // issue A(ks+2) loads
        }
        #pragma unroll
        for (int p = 0; p < 2; ++p) {                // two mi-pairs: 8 A LDS reads total
            half8 fah[2], fal[2];
            #pragma unroll
            for (int m = 0; m < 2; ++m) {
                int ca = lg * 256 + wm + (p * 2 + m) * 16 + l15;
                fah[m] = Ah[buf][ca];
                fal[m] = Al[buf][ca];
            }
            #pragma unroll
            for (int nj = 0; nj < 4; ++nj) {
                size_t fo = (size_t)(((c4base + nj) * 16 + ks)) << 9;  // *512 halfs
                half8 fbh = *reinterpret_cast<const half8*>(fbh_base + fo);
                half8 fbl = *reinterpret_cast<const half8*>(fbl_base + fo);
                #pragma unroll
                for (int m = 0; m < 2; ++m) {
                    int mi = p * 2 + m;
                    acc[mi][nj] = __builtin_amdgcn_mfma_f32_16x16x32_f16(fah[m], fbh, acc[mi][nj], 0, 0, 0);
                    f32x4 t = __builtin_amdgcn_mfma_f32_16x16x32_f16(fah[m], fbl, (f32x4){0.f,0.f,0.f,0.f}, 0, 0, 0);
                    t = __builtin_amdgcn_mfma_f32_16x16x32_f16(fal[m], fbh, t, 0, 0, 0);
                    acc[mi][nj] += t * (1.0f / 2048.0f);
                }
            }
        }
        __syncthreads();
    }

    // ---- epilogue: z = acc + b1 ; exact GELU ; dot W2 ; reduce 16 lanes + 2 N-waves ----
    float b1v[4], w2v[4];
    #pragma unroll
    for (int nj = 0; nj < 4; ++nj) {
        int col = colhalf * 128 + wnx * 64 + nj * 16 + l15;
        b1v[nj] = b1[col];
        w2v[nj] = W2[col];
    }
    float part[4][4];
    #pragma unroll
    for (int mi = 0; mi < 4; ++mi)
        #pragma unroll
        for (int r = 0; r < 4; ++r)
            part[mi][r] = 0.f;
    #pragma unroll
    for (int mi = 0; mi < 4; ++mi)
        #pragma unroll
        for (int nj = 0; nj < 4; ++nj)
            #pragma unroll
            for (int r = 0; r < 4; ++r) {
                float z = acc[mi][nj][r] + b1v[nj];
                float g = 0.5f * z * (1.0f + erff(z * 0.70710678118654752440f));
                part[mi][r] = fmaf(g, w2v[nj], part[mi][r]);
            }
    float* red = reinterpret_cast<float*>(&Ah[0][0]);  // dead A buffer; 2*256 floats
    #pragma unroll
    for (int mi = 0; mi < 4; ++mi)
        #pragma unroll
        for (int r = 0; r < 4; ++r) {
            float v = part[mi][r];
            v += __shfl_xor(v, 1, 16);
            v += __shfl_xor(v, 2, 16);
            v += __shfl_xor(v, 4, 16);
            v += __shfl_xor(v, 8, 16);
            if (l15 == 0)
                red[wnx * 256 + wm + mi * 16 + lg * 4 + r] = v;
        }
    __syncthreads();
    if (tid < 256)
        lp[(size_t)colhalf * 65536 + row0 + tid] = red[tid] + red[256 + tid];
}

// ---------------- Kernel 2: softmax + top-8 + mask/importance/indices ----------------
__global__ __launch_bounds__(256) void softmax_topk_kernel(
    const float* __restrict__ lp,          // (2, 65536) partial logits
    const float* __restrict__ b2p,
    const float* __restrict__ base_logits,
    float* __restrict__ out_mask,
    float* __restrict__ out_importance,
    float* __restrict__ out_indices)
{
    const int b = blockIdx.x;
    const int tid = threadIdx.x;
    __shared__ float probs[N_DIM];
    __shared__ float redf[4];
    __shared__ int   redi[4];
    __shared__ int   sel_idx[K_SEL];

    const float b2v = b2p[0];
    int i0g = b * N_DIM + tid;
    int i1g = i0g + 256;
    float l0 = lp[i0g] + lp[65536 + i0g] + b2v + base_logits[tid];
    float l1 = lp[i1g] + lp[65536 + i1g] + b2v + base_logits[tid + 256];

    float m = fmaxf(l0, l1);
    #pragma unroll
    for (int s = 32; s >= 1; s >>= 1) m = fmaxf(m, __shfl_xor(m, s, 64));
    if ((tid & 63) == 0) redf[tid >> 6] = m;
    __syncthreads();
    float gm = fmaxf(fmaxf(redf[0], redf[1]), fmaxf(redf[2], redf[3]));
    __syncthreads();

    float e0 = expf(l0 - gm), e1 = expf(l1 - gm);
    float ssum = e0 + e1;
    #pragma unroll
    for (int s = 32; s >= 1; s >>= 1) ssum += __shfl_xor(ssum, s, 64);
    if ((tid & 63) == 0) redf[tid >> 6] = ssum;
    __syncthreads();
    float denom = redf[0] + redf[1] + redf[2] + redf[3];
    float p0 = e0 / denom, p1 = e1 / denom;
    probs[tid] = p0;
    probs[tid + 256] = p1;
    out_importance[b * N_DIM + tid] = p0;
    out_importance[b * N_DIM + tid + 256] = p1;
    __syncthreads();

    for (int it = 0; it < K_SEL; ++it) {
        float v0 = probs[tid]; int i0 = tid;
        float v1 = probs[tid + 256];
        if (v1 > v0) { v0 = v1; i0 = tid + 256; }
        #pragma unroll
        for (int s = 32; s >= 1; s >>= 1) {
            float ov = __shfl_xor(v0, s, 64);
            int   oi = __shfl_xor(i0, s, 64);
            if (ov > v0 || (ov == v0 && oi < i0)) { v0 = ov; i0 = oi; }
        }
        if ((tid & 63) == 0) { redf[tid >> 6] = v0; redi[tid >> 6] = i0; }
        __syncthreads();
        if (tid == 0) {
            float bv = redf[0]; int bi = redi[0];
            for (int w = 1; w < 4; ++w)
                if (redf[w] > bv || (redf[w] == bv && redi[w] < bi)) { bv = redf[w]; bi = redi[w]; }
            sel_idx[it] = bi;
            probs[bi] = -1.0f;
        }
        __syncthreads();
    }

    float mk0 = 0.f, mk1 = 0.f;
    #pragma unroll
    for (int i = 0; i < K_SEL; ++i) {
        if (sel_idx[i] == tid)       mk0 = 1.f;
        if (sel_idx[i] == tid + 256) mk1 = 1.f;
    }
    out_mask[b * N_DIM + tid] = mk0;
    out_mask[b * N_DIM + tid + 256] = mk1;

    if (tid < K_SEL) out_indices[b * K_SEL + tid] = (float)sel_idx[tid];
}

// ---------------- Kernel 3: gather selected rows (overwrites scratch last) ----------
__global__ __launch_bounds__(256) void gather_kernel(
    const float* __restrict__ X,
    const float* __restrict__ out_indices,
    float* __restrict__ out_selected)
{
    const int b = blockIdx.x;
    const int tid = threadIdx.x;
    __shared__ int sel[K_SEL];
    if (tid < K_SEL) sel[tid] = (int)out_indices[b * K_SEL + tid];
    __syncthreads();
    #pragma unroll
    for (int i = 0; i < 4; ++i) {
        int f = tid + 256 * i;
        int ki = f >> 7;
        int c4 = f & 127;
        float4 v = reinterpret_cast<const float4*>(
            X + ((size_t)b * N_DIM + sel[ki]) * D_DIM)[c4];
        reinterpret_cast<float4*>(
            out_selected + ((size_t)b * K_SEL + ki) * D_DIM)[c4] = v;
    }
}

extern "C" void kernel_launch(void* const* d_in, const int* in_sizes, int n_in,
                              void* d_out, int out_size, void* d_ws, size_t ws_size,
                              hipStream_t stream) {
    const float* X           = (const float*)d_in[0];
    const float* W1          = (const float*)d_in[1];
    const float* b1          = (const float*)d_in[2];
    const float* W2          = (const float*)d_in[3];
    const float* b2          = (const float*)d_in[4];
    const float* base_logits = (const float*)d_in[5];

    float* out            = (float*)d_out;
    float* out_selected   = out;                                  // 128*8*512 = 524288
    float* out_mask       = out_selected + B_DIM * K_SEL * D_DIM; // 128*512
    float* out_importance = out_mask + B_DIM * N_DIM;             // 128*512
    float* out_indices    = out_importance + B_DIM * N_DIM;       // 128*8

    // Scratch inside out_selected's region (gather overwrites it last):
    //   [0      .. 131072) lp: 2 x 65536 partial logits (f32)
    //   [131072 .. 196608) w1frag_h (131072 halfs)
    //   [196608 .. 262144) w1frag_l (131072 halfs)
    float*    lp       = out_selected;
    _Float16* w1frag_h = (_Float16*)(out_selected + 131072);
    _Float16* w1frag_l = (_Float16*)(out_selected + 196608);

    hipLaunchKernelGGL(prep_w1_kernel, dim3(256), dim3(512), 0, stream,
                       W1, w1frag_h, w1frag_l);
    hipLaunchKernelGGL(fused_scorer_mfma, dim3(512), dim3(512), 0, stream,
                       X, w1frag_h, w1frag_l, b1, W2, lp);
    hipLaunchKernelGGL(softmax_topk_kernel, dim3(B_DIM), dim3(256), 0, stream,
                       lp, b2, base_logits, out_mask, out_importance, out_indices);
    hipLaunchKernelGGL(gather_kernel, dim3(B_DIM), dim3(256), 0, stream,
                       X, out_indices, out_selected);
}